// Round 17
// baseline (1622.328 us; speedup 1.0000x reference)
//
#include <hip/hip_runtime.h>
#include <math.h>

#define TID ((int)threadIdx.x)

namespace {
constexpr float EPSf = 1e-5f;

typedef __attribute__((ext_vector_type(8))) short short8;   // 8 bf16 (4 VGPR)
typedef __attribute__((ext_vector_type(4))) float f32x4;

struct FpsArgs {
  const float* pts; float* out; float* dmin; int* far;
  int it0, it1, nc;
};

__device__ __forceinline__ unsigned fenc(float f){
  unsigned u = __float_as_uint(f);
  return (u & 0x80000000u) ? ~u : (u | 0x80000000u);
}
__device__ __forceinline__ float fdec(unsigned e){
  unsigned u = (e & 0x80000000u) ? (e & 0x7fffffffu) : ~e;
  return __uint_as_float(u);
}
__device__ __forceinline__ short bf16rne(float f){
  unsigned u = __float_as_uint(f);
  return (short)((u + 0x7fffu + ((u >> 16) & 1u)) >> 16);
}

template<int CTRL>
__device__ __forceinline__ void dpp_comb(float& bm, int& bp){
  int om_i = __builtin_amdgcn_update_dpp(__float_as_int(bm), __float_as_int(bm), CTRL, 0xf, 0xf, false);
  int op   = __builtin_amdgcn_update_dpp(bp, bp, CTRL, 0xf, 0xf, false);
  float om = __int_as_float(om_i);
  if (om > bm || (om == bm && op < bp)){ bm = om; bp = op; }
}

// ---------------- FPS body (sidecar blocks inside other kernels) -----------
template<int LP, int NT>
__device__ void fps_body(const FpsArgs& a, int ci){
  const int NPTS = NT*LP;
  const float* pts = a.pts + (size_t)ci * NPTS * 3;
  float* out = a.out + (size_t)ci * 512 * 3;
  float* dst = a.dmin + (size_t)ci * NPTS;
  float px[LP], py[LP], pz[LP], dmin[LP];
#pragma unroll
  for (int j = 0; j < LP; j++){
    int p = TID + NT*j;
    px[j] = pts[p*3+0]; py[j] = pts[p*3+1]; pz[j] = pts[p*3+2];
  }
  int far;
  if (a.it0 == 0){
#pragma unroll
    for (int j = 0; j < LP; j++) dmin[j] = 1e10f;
    far = 0;
  } else {
#pragma unroll
    for (int j = 0; j < LP; j++) dmin[j] = dst[TID + NT*j];
    far = a.far[ci];
  }
  __shared__ unsigned long long red2[2][NT/64];
  for (int i = a.it0; i < a.it1; i++){
    float cx = pts[far*3+0], cy = pts[far*3+1], cz = pts[far*3+2];
    if (TID == 0){ out[i*3+0]=cx; out[i*3+1]=cy; out[i*3+2]=cz; }
    float bm = -1.f; int bp = 0;
#pragma unroll
    for (int j = 0; j < LP; j++){
      float dx = __fsub_rn(px[j], cx);
      float dy = __fsub_rn(py[j], cy);
      float dz = __fsub_rn(pz[j], cz);
      float d  = __fadd_rn(__fadd_rn(__fmul_rn(dx,dx), __fmul_rn(dy,dy)), __fmul_rn(dz,dz));
      float dm = fminf(dmin[j], d);
      dmin[j] = dm;
      if (dm > bm){ bm = dm; bp = TID + NT*j; }
    }
    dpp_comb<0x111>(bm,bp); dpp_comb<0x112>(bm,bp); dpp_comb<0x114>(bm,bp);
    dpp_comb<0x118>(bm,bp); dpp_comb<0x142>(bm,bp); dpp_comb<0x143>(bm,bp);
    unsigned long long key =
      ((unsigned long long)(unsigned)__builtin_amdgcn_readlane(__float_as_int(bm), 63) << 32)
      | (unsigned)~(unsigned)__builtin_amdgcn_readlane(bp, 63);
    if ((TID & 63) == 63) red2[i&1][TID>>6] = key;
    __syncthreads();
    unsigned long long kk = red2[i&1][0];
#pragma unroll
    for (int t = 1; t < NT/64; t++){
      unsigned long long o = red2[i&1][t];
      kk = kk > o ? kk : o;
    }
    far = (int)~(unsigned)kk;
  }
  if (a.it1 < 512){
#pragma unroll
    for (int j = 0; j < LP; j++) dst[TID + NT*j] = dmin[j];
    if (TID == 0) a.far[ci] = far;
  }
}

// ---------------- small row-GEMM with optional BN(+relu) on input load -----
template<int C, int K, int FLP>
__global__ void __launch_bounds__(256) rowgemm_kernel(const float* __restrict__ in,
    const float* __restrict__ w, const float* __restrict__ bias, const float2* __restrict__ st2,
    float* __restrict__ out, int rows_per_g, FpsArgs fa)
{
  int bid = blockIdx.x;
  if constexpr (FLP > 0){
    if (bid < fa.nc){ fps_body<FLP,256>(fa, bid); return; }
    bid -= fa.nc;
  }
  constexpr int RPB = 256 / C;
  __shared__ float lin[RPB * K];
  size_t row0 = (size_t)bid * RPB;
  int g = (int)(row0 / rows_per_g);
  for (int i = TID; i < RPB*K; i += 256){
    float v = in[row0*(size_t)K + i];
    if (st2){ float2 s = st2[(size_t)g*K + (i % K)]; v = fmaxf((v - s.x)*s.y, 0.f); }
    lin[i] = v;
  }
  __syncthreads();
  int r = TID / C, c = TID % C;
  float acc = bias[(size_t)g*C + c];
  const float* wg = w + (size_t)g*K*C + c;
#pragma unroll
  for (int k = 0; k < K; k++) acc = fmaf(lin[r*K + k], wg[(size_t)k*C], acc);
  out[(row0 + r)*C + c] = acc;
}

// ---------------- pointnet L3 via MFMA: 128 rows/block, 8 col-slabs --------
template<int FLP>
__global__ void __launch_bounds__(256, 4) big1024m_kernel(const float* __restrict__ in,
    const float2* __restrict__ st2, const short* __restrict__ wtp,
    float* __restrict__ ps, float* __restrict__ pq, unsigned* __restrict__ maxenc, FpsArgs fa)
{
  int bid = blockIdx.x;
  if constexpr (FLP > 0){
    if (bid < fa.nc){ fps_body<FLP,256>(fa, bid); return; }
    bid -= fa.nc;
  }
  size_t row0 = (size_t)bid * 128;
  int b = (int)(row0 >> 11);
  __shared__ float2 sb[128];
  __shared__ float mS[512], mQ[512], mM[512];
  if (TID < 128) sb[TID] = st2[TID];
  __syncthreads();
  int lane = TID & 63, wid = TID >> 6, lr = lane & 15, lkg = lane >> 4;

  short8 afr[4][2];
  const float* src = in + row0*128;
#pragma unroll
  for (int kt = 0; kt < 4; kt++){
    int kb = kt*32 + lkg*8;
    float2 ss[8];
#pragma unroll
    for (int j = 0; j < 8; j++) ss[j] = sb[kb + j];
#pragma unroll
    for (int nt = 0; nt < 2; nt++){
      int row = wid*32 + nt*16 + lr;
      float4 a0 = *(const float4*)(src + row*128 + kb);
      float4 a1 = *(const float4*)(src + row*128 + kb + 4);
      const float vals[8] = {a0.x,a0.y,a0.z,a0.w,a1.x,a1.y,a1.z,a1.w};
      short8 ob;
#pragma unroll
      for (int j = 0; j < 8; j++)
        ob[j] = bf16rne(fmaxf((vals[j] - ss[j].x)*ss[j].y, 0.f));
      afr[kt][nt] = ob;
    }
  }

  for (int cs = 0; cs < 8; cs++){
    f32x4 acc[2][8];
#pragma unroll
    for (int nt = 0; nt < 2; nt++)
#pragma unroll
      for (int et = 0; et < 8; et++) acc[nt][et] = (f32x4){0.f,0.f,0.f,0.f};
    const short* wp = wtp + (size_t)(cs*128)*128;
#pragma unroll
    for (int kt = 0; kt < 4; kt++){
      int kb = kt*32 + lkg*8;
#pragma unroll
      for (int et = 0; et < 8; et++){
        short8 bfr = *(const short8*)&wp[(et*16 + lr)*128 + kb];
        acc[0][et] = __builtin_amdgcn_mfma_f32_16x16x32_bf16(afr[kt][0], bfr, acc[0][et], 0, 0, 0);
        acc[1][et] = __builtin_amdgcn_mfma_f32_16x16x32_bf16(afr[kt][1], bfr, acc[1][et], 0, 0, 0);
      }
    }
#pragma unroll
    for (int et = 0; et < 8; et++){
      float s = 0.f, q = 0.f, m = -1e38f;
#pragma unroll
      for (int nt = 0; nt < 2; nt++)
#pragma unroll
        for (int r = 0; r < 4; r++){
          float v = acc[nt][et][r];
          s += v; q = fmaf(v, v, q); m = fmaxf(m, v);
        }
      s += __shfl_xor(s, 16); s += __shfl_xor(s, 32);
      q += __shfl_xor(q, 16); q += __shfl_xor(q, 32);
      m = fmaxf(m, __shfl_xor(m, 16)); m = fmaxf(m, __shfl_xor(m, 32));
      if (lkg == 0){
        mS[wid*128 + et*16 + lr] = s;
        mQ[wid*128 + et*16 + lr] = q;
        mM[wid*128 + et*16 + lr] = m;
      }
    }
    __syncthreads();
    if (wid == 0){
#pragma unroll
      for (int t = 0; t < 2; t++){
        int c = t*64 + lane;
        float s4 = mS[c] + mS[128 + c] + mS[256 + c] + mS[384 + c];
        float q4 = mQ[c] + mQ[128 + c] + mQ[256 + c] + mQ[384 + c];
        float m4 = fmaxf(fmaxf(mM[c], mM[128 + c]), fmaxf(mM[256 + c], mM[384 + c]));
        ps[(size_t)bid*1024 + cs*128 + c] = s4;
        pq[(size_t)bid*1024 + cs*128 + c] = q4;
        atomicMax(&maxenc[(size_t)b*1024 + cs*128 + c], fenc(m4));
      }
    }
    __syncthreads();
  }
}

// ---------------- mapping GEMM v2: 8b x 4j tile, broadcast LDS lin ---------
template<int FLP>
__global__ void __launch_bounds__(128) mapgemm2_kernel(const float* __restrict__ in, int in_gstride,
    const float* __restrict__ w, const float* __restrict__ bias, const float2* __restrict__ st2,
    float* __restrict__ out, int K, int J, int JB, int NS, FpsArgs fa)
{
  int bid = blockIdx.x;
  if constexpr (FLP > 0){
    if (bid < fa.nc){ fps_body<FLP,128>(fa, bid); return; }
    bid -= fa.nc;
  }
  int kc = bid / (JB*16);
  int g  = (bid / JB) % 16;
  int jb = bid % JB;
  int kchunk = K / NS, k0 = kc*kchunk;
  __shared__ float linT[128*16];
  const float* ing = in + (size_t)g * in_gstride;
  for (int i = TID; i < kchunk*16; i += 128){
    int b = i / kchunk, k = i - b*kchunk;
    float v = ing[(size_t)b*K + k0 + k];
    if (st2){ float2 s = st2[(size_t)g*K + k0 + k]; v = fmaxf((v - s.x)*s.y, 0.f); }
    linT[k*16 + b] = v;
  }
  __syncthreads();
  int bh = TID >> 6, jq = TID & 63;
  int j = jb*256 + jq*4;
  const float* wp = w + ((size_t)g*K + k0)*J + j;
  float4 a4[8];
#pragma unroll
  for (int bi = 0; bi < 8; bi++) a4[bi] = make_float4(0.f,0.f,0.f,0.f);
#pragma unroll 4
  for (int k = 0; k < kchunk; k++){
    float4 wv = *(const float4*)(wp + (size_t)k*J);
    float4 l0 = *(const float4*)&linT[k*16 + bh*8];
    float4 l1 = *(const float4*)&linT[k*16 + bh*8 + 4];
    const float lv[8] = {l0.x,l0.y,l0.z,l0.w,l1.x,l1.y,l1.z,l1.w};
#pragma unroll
    for (int bi = 0; bi < 8; bi++){
      a4[bi].x = fmaf(lv[bi], wv.x, a4[bi].x);
      a4[bi].y = fmaf(lv[bi], wv.y, a4[bi].y);
      a4[bi].z = fmaf(lv[bi], wv.z, a4[bi].z);
      a4[bi].w = fmaf(lv[bi], wv.w, a4[bi].w);
    }
  }
  if (NS == 1){
    float4 bv = *(const float4*)(bias + (size_t)g*J + j);
#pragma unroll
    for (int bi = 0; bi < 8; bi++){
      int b = bh*8 + bi;
      float4 o = make_float4(a4[bi].x+bv.x, a4[bi].y+bv.y, a4[bi].z+bv.z, a4[bi].w+bv.w);
      *(float4*)&out[((size_t)g*16 + b)*J + j] = o;
    }
  } else {
#pragma unroll
    for (int bi = 0; bi < 8; bi++)
      *(float4*)&out[(((size_t)kc*16 + g)*16 + bh*8 + bi)*J + j] = a4[bi];
  }
}

// ---------------- old skinny per-g GEMM (kept for mp_w4, J=128; NS chunk
// must be a multiple of 128 -- stage stride is hard-wired) ------------------
__global__ void __launch_bounds__(256) mapgemm_kernel(const float* __restrict__ in, int in_gstride,
    const float* __restrict__ w, const float* __restrict__ bias, const float2* __restrict__ st2,
    float* __restrict__ out, int K, int J, int JB, int NS)
{
  int bid = blockIdx.x;
  int kc = bid / (JB*16);
  int g  = (bid / JB) % 16;
  int jb = bid % JB;
  int j  = jb*256 + TID;
  bool jv = j < J;
  int jc = jv ? j : 0;
  int kchunk = K / NS;
  int k0 = kc * kchunk;
  __shared__ float lin[16 * 128];
  const float* ing = in + (size_t)g * in_gstride;
  float acc[16];
  float bv = (NS == 1 && jv) ? bias[(size_t)g*J + jc] : 0.f;
#pragma unroll
  for (int b = 0; b < 16; b++) acc[b] = bv;
  for (int kt = k0; kt < k0 + kchunk; kt += 128){
    __syncthreads();
    for (int i = TID; i < 2048; i += 256){
      int b = i >> 7, k = i & 127;
      float v = ing[(size_t)b*K + kt + k];
      if (st2){ float2 s = st2[(size_t)g*K + kt + k]; v = fmaxf((v - s.x)*s.y, 0.f); }
      lin[i] = v;
    }
    __syncthreads();
    const float* wg = w + ((size_t)g*K + kt)*J + jc;
    for (int k = 0; k < 128; k++){
      float wv = wg[(size_t)k*J];
#pragma unroll
      for (int b = 0; b < 16; b++) acc[b] = fmaf(lin[b*128 + k], wv, acc[b]);
    }
  }
  if (jv){
    if (NS == 1){
      for (int b = 0; b < 16; b++) out[((size_t)g*16 + b)*J + j] = acc[b];
    } else {
      for (int b = 0; b < 16; b++) out[(((size_t)kc*16 + g)*16 + b)*J + j] = acc[b];
    }
  }
}

__global__ void __launch_bounds__(256) redstats_kernel(const float* __restrict__ part,
    const float* __restrict__ bias, float* __restrict__ out, float2* __restrict__ st2,
    int J, int NS)
{
  int t = blockIdx.x*256 + TID;
  int g = t / J, j = t % J;
  float bv = bias[t];
  float s = 0.f, q = 0.f;
  for (int b = 0; b < 16; b++){
    float v = bv;
    for (int c = 0; c < NS; c++) v += part[(((size_t)c*16 + g)*16 + b)*J + j];
    out[((size_t)g*16 + b)*J + j] = v;
    s += v; q = fmaf(v, v, q);
  }
  float mean = s * (1.f/16.f);
  float var  = q * (1.f/16.f) - mean*mean;
  st2[t] = make_float2(mean, rsqrtf(fmaxf(var, 0.f) + EPSf));
}

// chunked coalesced BN partial sums (optionally hosts fps sidecar) ----------
template<int FLP>
__global__ void __launch_bounds__(256) statsacc_kernel(const float* __restrict__ in,
    float* __restrict__ part, int C, size_t chunk, FpsArgs fa)
{
  int bid = blockIdx.x;
  if constexpr (FLP > 0){
    if (bid < fa.nc){ fps_body<FLP,256>(fa, bid); return; }
    bid -= fa.nc;
  }
  size_t base = (size_t)bid * chunk;
  int c = TID % C;
  float s = 0.f, q = 0.f;
  for (size_t idx = base + TID; idx < base + chunk; idx += 256){
    float v = in[idx]; s += v; q = fmaf(v, v, q);
  }
  __shared__ float ls[256], lq[256];
  ls[TID] = s; lq[TID] = q; __syncthreads();
  if (TID < C){
    for (int t = TID + C; t < 256; t += C){ s += ls[t]; q += lq[t]; }
    part[((size_t)bid*C + c)*2]   = s;
    part[((size_t)bid*C + c)*2+1] = q;
  }
}

__global__ void statsfin_kernel(const float* __restrict__ part, float2* __restrict__ st2,
    int C, int G, float invR)
{
  int slot = blockIdx.x*256 + TID;
  if (slot >= G*C) return;
  int g = slot / C, c = slot % C;
  int bpg = 256 / G;
  float s = 0.f, q = 0.f;
  for (int b = 0; b < bpg; b++){
    size_t p = ((size_t)(g*bpg + b)*C + c)*2;
    s += part[p]; q += part[p+1];
  }
  float mean = s*invR;
  float var  = q*invR - mean*mean;
  st2[slot] = make_float2(mean, rsqrtf(fmaxf(var, 0.f) + EPSf));
}

// PointNet L3: reduce 256 per-block partials -> per-channel (mean,rstd) -----
__global__ void pnfin_kernel(const float* __restrict__ ps, const float* __restrict__ pq,
                             float2* __restrict__ st)
{
  int c = blockIdx.x*256 + TID;
  float s = 0.f, q = 0.f;
  for (int rb = 0; rb < 256; rb++){ s += ps[rb*1024 + c]; q += pq[rb*1024 + c]; }
  float mean = s * (1.f/32768.f);
  float var  = q * (1.f/32768.f) - mean*mean;
  st[c] = make_float2(mean, rsqrtf(fmaxf(var, 0.f) + EPSf));
}

__global__ void feat_kernel(const unsigned* __restrict__ me, const float2* __restrict__ st,
                            float* __restrict__ feat)
{
  int t = blockIdx.x*256 + TID;
  int c = t & 1023;
  float2 s = st[c];
  feat[t] = (fdec(me[t]) - s.x) * s.y;
}

// ---------------- W transpose+cvt: Wt[g][e][k] bf16 (128k x 1024e per g) ---
__global__ void __launch_bounds__(256) wtr_kernel(const float* __restrict__ c3w,
                                                  short* __restrict__ wt)
{
  int g = blockIdx.x >> 4, kt = blockIdx.x & 15;
  __shared__ float lds[8*1024];
  const float* src = c3w + ((size_t)g*128 + kt*8)*1024;
  for (int i = TID; i < 8192; i += 256) lds[i] = src[i];
  __syncthreads();
  for (int e = TID; e < 1024; e += 256){
    short8 v;
#pragma unroll
    for (int j = 0; j < 8; j++) v[j] = bf16rne(lds[j*1024 + e]);
    *(short8*)&wt[((size_t)g*1024 + e)*128 + kt*8] = v;
  }
}

// ---------------- fused v4.3: B staging software-pipelined (reg prefetch),
// 2 barriers/eb ------------------------------------------------------------
template<int FLP>
__global__ void __launch_bounds__(256, 2) fused_kernel(const float* __restrict__ c2o,
    const float2* __restrict__ st2, const short* __restrict__ wt,
    const float* __restrict__ xb, const float* __restrict__ c4w, const float* __restrict__ c4b,
    float* __restrict__ out_pts, float* __restrict__ out_x1, FpsArgs fa)
{
  int bid = blockIdx.x;
  if constexpr (FLP > 0){
    if (bid < fa.nc){ fps_body<FLP,256>(fa, bid); return; }
    bid -= fa.nc;
  }
  int gb = bid >> 1, ebh = bid & 1;
  int g = gb >> 4, b = gb & 15;
  __shared__ short Pbf[16384];     // P [128e][128n] bf16 swz (per eb)
  __shared__ short Bls[16384];     // B tile [128e][128k] bf16 swz (per eb)
  __shared__ short xbT[4096];      // [32k][128n] bf16 swz
  __shared__ float2 sb[128];       // BN (mean,rstd) for this g
  __shared__ float mred[512];      // [4 wid][128 e] sum partials

  if (TID < 128) sb[TID] = st2[(size_t)g*128 + TID];
  {
    const float* xsrc = xb + (size_t)gb*4096;
    for (int idx = TID; idx < 1024; idx += 256){
      int n = idx >> 3, k4 = (idx & 7)*4;
      float4 v = *(const float4*)(xsrc + n*32 + k4);
      const float vv[4] = {v.x, v.y, v.z, v.w};
#pragma unroll
      for (int j = 0; j < 4; j++){
        int k = k4 + j;
        xbT[k*128 + (((n >> 3) ^ (k & 7)) << 3) + (n & 7)] = bf16rne(vv[j]);
      }
    }
  }
  // stage B for first eb of this half
  const int eb0 = ebh*4;
  const short* wt_base = wt + (size_t)g*1024*128;
  {
    const short* wtg = wt_base + (size_t)(eb0*128)*128;
    for (int i = TID; i < 2048; i += 256){
      int e = i >> 4, kc = i & 15;
      short8 v = *(const short8*)&wtg[e*128 + kc*8];
      *(short8*)&Bls[e*128 + ((kc ^ (e & 7)) << 3)] = v;
    }
  }

  int lane = TID & 63, wid = TID >> 6;
  int lr = lane & 15, lkg = lane >> 4;

  // ---- A-frags: each (row,k8) loaded once, BN+relu+cvt in-reg ----
  // (sb read is safe: warp 0 wrote sb before reaching here? NO -- need
  //  barrier. The S0 barrier below covers sb + xbT + first Bls.)
  __syncthreads();   // S0: sb + xbT + Bls(eb0) ready

  short8 afr[4][2];
  const float* src = c2o + (size_t)gb*16384;
#pragma unroll
  for (int kt = 0; kt < 4; kt++){
    int kb = kt*32 + lkg*8;
    float2 ss[8];
#pragma unroll
    for (int j = 0; j < 8; j++) ss[j] = sb[kb + j];
#pragma unroll
    for (int nt = 0; nt < 2; nt++){
      int row = wid*32 + nt*16 + lr;
      float4 a0 = *(const float4*)(src + row*128 + kb);
      float4 a1 = *(const float4*)(src + row*128 + kb + 4);
      const float vals[8] = {a0.x,a0.y,a0.z,a0.w,a1.x,a1.y,a1.z,a1.w};
      short8 ob;
#pragma unroll
      for (int j = 0; j < 8; j++)
        ob[j] = bf16rne(fmaxf((vals[j] - ss[j].x)*ss[j].y, 0.f));
      afr[kt][nt] = ob;
    }
  }

  float c4l[2][3];
  {
    const float* cw = c4w + g*96;
#pragma unroll
    for (int kt2 = 0; kt2 < 2; kt2++){
      int k = kt2*16 + lr;
      c4l[kt2][0] = cw[k*3+0]; c4l[kt2][1] = cw[k*3+1]; c4l[kt2][2] = cw[k*3+2];
    }
  }
  float cb0 = c4b[g*3+0], cb1 = c4b[g*3+1], cb2 = c4b[g*3+2];
  unsigned* Pu = (unsigned*)Pbf;

  for (int eb = eb0; eb < eb0 + 4; eb++){
    // ---- h-GEMM (B from LDS) ----
    f32x4 acc[2][8];
#pragma unroll
    for (int nt = 0; nt < 2; nt++)
#pragma unroll
      for (int et = 0; et < 8; et++) acc[nt][et] = (f32x4){0.f,0.f,0.f,0.f};
#pragma unroll
    for (int kt = 0; kt < 4; kt++){
      int kcf = kt*4 + lkg;
#pragma unroll
      for (int et = 0; et < 8; et++){
        int e = et*16 + lr;
        short8 bfr = *(const short8*)&Bls[e*128 + ((kcf ^ (e & 7)) << 3)];
        acc[0][et] = __builtin_amdgcn_mfma_f32_16x16x32_bf16(afr[kt][0], bfr, acc[0][et], 0, 0, 0);
        acc[1][et] = __builtin_amdgcn_mfma_f32_16x16x32_bf16(afr[kt][1], bfr, acc[1][et], 0, 0, 0);
      }
    }

    // ---- issue next eb's B loads into regs (latency hides under exp+PV) ----
    short8 bpre[8];
    bool havepre = (eb + 1 < eb0 + 4);
    if (havepre){
      const short* wtg = wt_base + (size_t)((eb+1)*128)*128;
#pragma unroll
      for (int ii = 0; ii < 8; ii++){
        int i = TID + 256*ii;
        int e = i >> 4, kc = i & 15;
        bpre[ii] = *(const short8*)&wtg[e*128 + kc*8];
      }
    }

    // ---- exp (no max), sum partials -> mred, P -> LDS bf16 [e][n] ----
#pragma unroll
    for (int et = 0; et < 8; et++){
      float ss = 0.f;
#pragma unroll
      for (int nt = 0; nt < 2; nt++)
#pragma unroll
        for (int r = 0; r < 4; r++){
          float p = __expf(acc[nt][et][r]);
          acc[nt][et][r] = p;
          ss += p;
        }
      ss += __shfl_xor(ss, 16);
      ss += __shfl_xor(ss, 32);
      if (lkg == 0) mred[wid*128 + et*16 + lr] = ss;
      int e = et*16 + lr;
#pragma unroll
      for (int nt = 0; nt < 2; nt++){
        int nb = wid*32 + nt*16 + lkg*4;
        int base = e*128 + ((((nb >> 3)) ^ (e & 7)) << 3) + (nb & 7);
        unsigned lo = (unsigned)(unsigned short)bf16rne(acc[nt][et][0])
                    | ((unsigned)(unsigned short)bf16rne(acc[nt][et][1]) << 16);
        unsigned hi = (unsigned)(unsigned short)bf16rne(acc[nt][et][2])
                    | ((unsigned)(unsigned short)bf16rne(acc[nt][et][3]) << 16);
        Pu[base >> 1]       = lo;
        Pu[(base >> 1) + 1] = hi;
      }
    }
    __syncthreads();   // S3: P + sums ready; ALL waves' h-GEMM Bls reads done

    // ---- commit prefetched B to Bls (safe after S3) ----
    if (havepre){
#pragma unroll
      for (int ii = 0; ii < 8; ii++){
        int i = TID + 256*ii;
        int e = i >> 4, kc = i & 15;
        *(short8*)&Bls[e*128 + ((kc ^ (e & 7)) << 3)] = bpre[ii];
      }
    }

    // ---- PV via MFMA: wave owns e-tiles wid*2, wid*2+1 ----
    f32x4 yy[2][2];
#pragma unroll
    for (int t2 = 0; t2 < 2; t2++){ yy[t2][0] = (f32x4){0.f,0.f,0.f,0.f}; yy[t2][1] = (f32x4){0.f,0.f,0.f,0.f}; }
#pragma unroll
    for (int nc = 0; nc < 4; nc++){
      short8 bfrs[2];
#pragma unroll
      for (int kt2 = 0; kt2 < 2; kt2++){
        int k = kt2*16 + lr;
        bfrs[kt2] = *(const short8*)&xbT[k*128 + (((nc*4 + lkg) ^ (k & 7)) << 3)];
      }
#pragma unroll
      for (int t2 = 0; t2 < 2; t2++){
        int e = (wid*2 + t2)*16 + lr;
        short8 afrp = *(const short8*)&Pbf[e*128 + (((nc*4 + lkg) ^ (e & 7)) << 3)];
        yy[t2][0] = __builtin_amdgcn_mfma_f32_16x16x32_bf16(afrp, bfrs[0], yy[t2][0], 0, 0, 0);
        yy[t2][1] = __builtin_amdgcn_mfma_f32_16x16x32_bf16(afrp, bfrs[1], yy[t2][1], 0, 0, 0);
      }
    }

    // ---- epilogue: 1/s from 4 direct mred reads ----
#pragma unroll
    for (int t2 = 0; t2 < 2; t2++){
#pragma unroll
      for (int r = 0; r < 4; r++){
        float o0 = yy[t2][0][r]*c4l[0][0] + yy[t2][1][r]*c4l[1][0];
        float o1 = yy[t2][0][r]*c4l[0][1] + yy[t2][1][r]*c4l[1][1];
        float o2 = yy[t2][0][r]*c4l[0][2] + yy[t2][1][r]*c4l[1][2];
#pragma unroll
        for (int d = 1; d < 16; d <<= 1){
          o0 += __shfl_xor(o0, d);
          o1 += __shfl_xor(o1, d);
          o2 += __shfl_xor(o2, d);
        }
        if (lr == 0){
          int e = (wid*2 + t2)*16 + lkg*4 + r;
          float s = mred[e] + mred[128 + e] + mred[256 + e] + mred[384 + e];
          float rs = 1.f / s;
          o0 = fmaf(o0, rs, cb0);
          o1 = fmaf(o1, rs, cb1);
          o2 = fmaf(o2, rs, cb2);
          int eg = eb*128 + e;
          size_t po = ((size_t)gb*1024 + eg)*3;
          out_pts[po+0] = o0; out_pts[po+1] = o1; out_pts[po+2] = o2;
          if (out_x1){
            size_t xo = (((size_t)b*16 + g)*1024 + eg)*3;
            out_x1[xo+0] = o0; out_x1[xo+1] = o1; out_x1[xo+2] = o2;
          }
        }
      }
    }
    __syncthreads();   // S5: PV/epilogue reads + Bls writes done -> next eb
  }
}

// ---------------- x_2 = concat(fps1, x_partial) + d2 -----------------------
__global__ void combine_kernel(const float* __restrict__ fps1, const float* __restrict__ xpart,
                               const float* __restrict__ d2, float* __restrict__ x2)
{
  size_t i = (size_t)blockIdx.x*256 + TID;
  if (i >= (size_t)16*16*1024*3) return;
  int c = (int)(i % 3);
  size_t t = i / 3;
  int e = (int)(t % 1024);
  size_t gb = t / 1024;
  int g = (int)(gb >> 4), b = (int)(gb & 15);
  float base;
  if (e < 512) base = fps1[(gb*512 + e)*3 + c];
  else         base = xpart[((size_t)b*512 + (e - 512))*3 + c];
  x2[(((size_t)b*16384) + (size_t)g*1024 + e)*3 + c] = base + d2[i];
}

} // anon namespace

extern "C" void kernel_launch(void* const* d_in, const int* in_sizes, int n_in,
                              void* d_out, int out_size, void* d_ws, size_t ws_size,
                              hipStream_t stream)
{
  (void)in_sizes; (void)n_in; (void)out_size; (void)ws_size;
  const float* x    = (const float*)d_in[0];
  const float* pnw1 = (const float*)d_in[1];
  const float* pnb1 = (const float*)d_in[2];
  const float* pnw2 = (const float*)d_in[3];
  const float* pnb2 = (const float*)d_in[4];
  const float* pnw3 = (const float*)d_in[5];
  const float* mpw[4] = {(const float*)d_in[7],(const float*)d_in[9],(const float*)d_in[11],(const float*)d_in[13]};
  const float* mpb[4] = {(const float*)d_in[8],(const float*)d_in[10],(const float*)d_in[12],(const float*)d_in[14]};

  float* ws = (float*)d_ws;
  size_t o = 0;
  auto alloc = [&](size_t n){ float* p = ws + o; o += n; return p; };
  float* x_partial = alloc(24576);
  float* feat      = alloc(16384);
  float* mfeat     = alloc(32768);
  float2* st_pn1   = (float2*)alloc(128);
  float2* st_pn2   = (float2*)alloc(256);
  float2* st_pn3   = (float2*)alloc(2048);
  float2* st_c1    = (float2*)alloc(2048);
  float2* st_c2    = (float2*)alloc(4096);
  float2* st_map0  = (float2*)alloc(32768);
  float2* st_map1  = (float2*)alloc(32768);
  float2* st_map2  = (float2*)alloc(32768);
  float2* st_map3  = (float2*)alloc(4096);
  float* sa_part   = alloc(65536);
  float* pn_ps     = alloc(262144);
  float* pn_pq     = alloc(262144);
  unsigned* maxenc = (unsigned*)alloc(16384);
  float* mapA      = alloc(262144);
  float* mapB      = alloc(262144);
  float* mpart     = alloc(4194304);
  float* xb        = alloc(1048576);
  float* c1o       = alloc(2097152);
  float* c2o       = alloc(4194304);
  float* x1g       = alloc(786432);
  float* d2buf     = alloc(786432);
  float* fps1b     = alloc(393216);
  float* fpsA_dmin = alloc(32768);
  int*   fpsA_far  = (int*)alloc(16);
  float* fpsB_dmin = alloc(262144);
  int*   fpsB_far  = (int*)alloc(256);
  short* wt_g      = (short*)alloc(1048576);
  short* wt_r      = (short*)alloc(1048576);
  short* wt_pn     = (short*)alloc(65536);     // 128x1024 bf16

  float* xout1 = (float*)d_out;
  float* xout2 = xout1 + 786432;

  hipMemsetAsync(maxenc, 0, 16384*sizeof(unsigned), stream);

  wtr_kernel<<<256, 256, 0, stream>>>((const float*)d_in[21], wt_g);
  wtr_kernel<<<256, 256, 0, stream>>>((const float*)d_in[31], wt_r);
  wtr_kernel<<<16, 256, 0, stream>>>(pnw3, wt_pn);

  FpsArgs f0{};
  FpsArgs fa{x, x_partial, fpsA_dmin, fpsA_far, 0, 0, 16};

  // ---- PointNet (fps-A rides as sidecar) ----
  fa.it0 = 0; fa.it1 = 64;
  rowgemm_kernel<64,3,8><<<8192+16, 256, 0, stream>>>(x, pnw1, pnb1, nullptr, c1o, 32768, fa);
  statsacc_kernel<0><<<256, 256, 0, stream>>>(c1o, sa_part, 64, 8192, f0);
  statsfin_kernel<<<1, 256, 0, stream>>>(sa_part, st_pn1, 64, 1, 1.f/32768.f);
  fa.it0 = 64; fa.it1 = 128;
  rowgemm_kernel<128,64,8><<<16384+16, 256, 0, stream>>>(c1o, pnw2, pnb2, st_pn1, c2o, 32768, fa);
  statsacc_kernel<0><<<256, 256, 0, stream>>>(c2o, sa_part, 128, 16384, f0);
  statsfin_kernel<<<1, 256, 0, stream>>>(sa_part, st_pn2, 128, 1, 1.f/32768.f);
  fa.it0 = 128; fa.it1 = 224;
  big1024m_kernel<8><<<256+16, 256, 0, stream>>>(c2o, st_pn2, wt_pn, pn_ps, pn_pq, maxenc, fa);
  pnfin_kernel<<<4, 256, 0, stream>>>(pn_ps, pn_pq, st_pn3);
  feat_kernel<<<64, 256, 0, stream>>>(maxenc, st_pn3, feat);

  // ---- Mapping MLP ----
  fa.it0 = 224; fa.it1 = 288;
  mapgemm2_kernel<16><<<1024+16, 128, 0, stream>>>(feat, 0,     mpw[0], nullptr, nullptr, mpart, 1024, 1024, 4, 16, fa);
  redstats_kernel<<<64, 256, 0, stream>>>(mpart, mpb[0], mapA, st_map0, 1024, 16);
  fa.it0 = 288; fa.it1 = 352;
  mapgemm2_kernel<16><<<1024+16, 128, 0, stream>>>(mapA, 16384, mpw[1], nullptr, st_map0, mpart, 1024, 1024, 4, 16, fa);
  redstats_kernel<<<64, 256, 0, stream>>>(mpart, mpb[1], mapB, st_map1, 1024, 16);
  fa.it0 = 352; fa.it1 = 416;
  mapgemm2_kernel<16><<<1024+16, 128, 0, stream>>>(mapB, 16384, mpw[2], nullptr, st_map1, mpart, 1024, 1024, 4, 16, fa);
  redstats_kernel<<<64, 256, 0, stream>>>(mpart, mpb[2], mapA, st_map2, 1024, 16);
  // mp_w4: NS=4 (kchunk must stay a multiple of 128)
  mapgemm_kernel<<<64, 256, 0, stream>>>(mapA, 16384, mpw[3], nullptr, st_map2, mpart, 1024, 128, 1, 4);
  redstats_kernel<<<8, 256, 0, stream>>>(mpart, mpb[3], mfeat, st_map3, 128, 4);

  // ---- Two AXform heads; fps-A finishes on head-0, fps-B rides head-1 ----
  for (int p = 0; p < 2; p++){
    const float* fw  = (const float*)d_in[15 + p*10 + 0];
    const float* fb  = (const float*)d_in[15 + p*10 + 1];
    const float* c1w = (const float*)d_in[15 + p*10 + 2];
    const float* c1b = (const float*)d_in[15 + p*10 + 3];
    const float* c2w = (const float*)d_in[15 + p*10 + 4];
    const float* c2b = (const float*)d_in[15 + p*10 + 5];
    const float* c4w = (const float*)d_in[15 + p*10 + 8];
    const float* c4b = (const float*)d_in[15 + p*10 + 9];

    if (p == 0){
      fa.it0 = 416; fa.it1 = 480;
      mapgemm2_kernel<16><<<256+16, 128, 0, stream>>>(mfeat, 2048, fw, fb, st_map3, xb, 128, 4096, 16, 1, fa);
      fa.it0 = 480; fa.it1 = 512;
      rowgemm_kernel<64,32,8><<<8192+16, 256, 0, stream>>>(xb, c1w, c1b, nullptr, c1o, 2048, fa);
      statsacc_kernel<0><<<256, 256, 0, stream>>>(c1o, sa_part, 64, 8192, f0);
      statsfin_kernel<<<4, 256, 0, stream>>>(sa_part, st_c1, 64, 16, 1.f/2048.f);
      rowgemm_kernel<128,64,0><<<16384, 256, 0, stream>>>(c1o, c2w, c2b, st_c1, c2o, 2048, f0);
      statsacc_kernel<0><<<256, 256, 0, stream>>>(c2o, sa_part, 128, 16384, f0);
      statsfin_kernel<<<8, 256, 0, stream>>>(sa_part, st_c2, 128, 16, 1.f/2048.f);
      fused_kernel<0><<<512, 256, 0, stream>>>(c2o, st_c2, wt_g, xb, c4w, c4b, x1g, xout1, f0);
    } else {
      FpsArgs fb_{x1g, fps1b, fpsB_dmin, fpsB_far, 0, 0, 256};
      fb_.it0 = 0; fb_.it1 = 48;
      mapgemm2_kernel<8><<<256+256, 128, 0, stream>>>(mfeat, 2048, fw, fb, st_map3, xb, 128, 4096, 16, 1, fb_);
      fb_.it0 = 48; fb_.it1 = 144;
      rowgemm_kernel<64,32,4><<<8192+256, 256, 0, stream>>>(xb, c1w, c1b, nullptr, c1o, 2048, fb_);
      fb_.it0 = 144; fb_.it1 = 176;
      statsacc_kernel<4><<<256+256, 256, 0, stream>>>(c1o, sa_part, 64, 8192, fb_);
      statsfin_kernel<<<4, 256, 0, stream>>>(sa_part, st_c1, 64, 16, 1.f/2048.f);
      fb_.it0 = 176; fb_.it1 = 288;
      rowgemm_kernel<128,64,4><<<16384+256, 256, 0, stream>>>(c1o, c2w, c2b, st_c1, c2o, 2048, fb_);
      fb_.it0 = 288; fb_.it1 = 320;
      statsacc_kernel<4><<<256+256, 256, 0, stream>>>(c2o, sa_part, 128, 16384, fb_);
      statsfin_kernel<<<8, 256, 0, stream>>>(sa_part, st_c2, 128, 16, 1.f/2048.f);
      fb_.it0 = 320; fb_.it1 = 512;
      fused_kernel<4><<<512+256, 256, 0, stream>>>(c2o, st_c2, wt_r, xb, c4w, c4b, d2buf, nullptr, fb_);
    }
  }

  combine_kernel<<<3072, 256, 0, stream>>>(fps1b, x_partial, d2buf, xout2);
}

// Round 18
// 1593.993 us; speedup vs baseline: 1.0178x; 1.0178x over previous
//
#include <hip/hip_runtime.h>
#include <math.h>

#define TID ((int)threadIdx.x)

namespace {
constexpr float EPSf = 1e-5f;

typedef __attribute__((ext_vector_type(8))) short short8;   // 8 bf16 (4 VGPR)
typedef __attribute__((ext_vector_type(4))) float f32x4;

struct FpsArgs {
  const float* pts; float* out; float* dmin; int* far;
  int it0, it1, nc;
};

__device__ __forceinline__ unsigned fenc(float f){
  unsigned u = __float_as_uint(f);
  return (u & 0x80000000u) ? ~u : (u | 0x80000000u);
}
__device__ __forceinline__ float fdec(unsigned e){
  unsigned u = (e & 0x80000000u) ? (e & 0x7fffffffu) : ~e;
  return __uint_as_float(u);
}
__device__ __forceinline__ short bf16rne(float f){
  unsigned u = __float_as_uint(f);
  return (short)((u + 0x7fffu + ((u >> 16) & 1u)) >> 16);
}

template<int CTRL>
__device__ __forceinline__ void dpp_comb(float& bm, int& bp){
  int om_i = __builtin_amdgcn_update_dpp(__float_as_int(bm), __float_as_int(bm), CTRL, 0xf, 0xf, false);
  int op   = __builtin_amdgcn_update_dpp(bp, bp, CTRL, 0xf, 0xf, false);
  float om = __int_as_float(om_i);
  if (om > bm || (om == bm && op < bp)){ bm = om; bp = op; }
}

// ---------------- FPS body (sidecar blocks inside other kernels) -----------
template<int LP, int NT>
__device__ void fps_body(const FpsArgs& a, int ci){
  const int NPTS = NT*LP;
  const float* pts = a.pts + (size_t)ci * NPTS * 3;
  float* out = a.out + (size_t)ci * 512 * 3;
  float* dst = a.dmin + (size_t)ci * NPTS;
  float px[LP], py[LP], pz[LP], dmin[LP];
#pragma unroll
  for (int j = 0; j < LP; j++){
    int p = TID + NT*j;
    px[j] = pts[p*3+0]; py[j] = pts[p*3+1]; pz[j] = pts[p*3+2];
  }
  int far;
  if (a.it0 == 0){
#pragma unroll
    for (int j = 0; j < LP; j++) dmin[j] = 1e10f;
    far = 0;
  } else {
#pragma unroll
    for (int j = 0; j < LP; j++) dmin[j] = dst[TID + NT*j];
    far = a.far[ci];
  }
  __shared__ unsigned long long red2[2][NT/64];
  for (int i = a.it0; i < a.it1; i++){
    float cx = pts[far*3+0], cy = pts[far*3+1], cz = pts[far*3+2];
    if (TID == 0){ out[i*3+0]=cx; out[i*3+1]=cy; out[i*3+2]=cz; }
    float bm = -1.f; int bp = 0;
#pragma unroll
    for (int j = 0; j < LP; j++){
      float dx = __fsub_rn(px[j], cx);
      float dy = __fsub_rn(py[j], cy);
      float dz = __fsub_rn(pz[j], cz);
      float d  = __fadd_rn(__fadd_rn(__fmul_rn(dx,dx), __fmul_rn(dy,dy)), __fmul_rn(dz,dz));
      float dm = fminf(dmin[j], d);
      dmin[j] = dm;
      if (dm > bm){ bm = dm; bp = TID + NT*j; }
    }
    dpp_comb<0x111>(bm,bp); dpp_comb<0x112>(bm,bp); dpp_comb<0x114>(bm,bp);
    dpp_comb<0x118>(bm,bp); dpp_comb<0x142>(bm,bp); dpp_comb<0x143>(bm,bp);
    unsigned long long key =
      ((unsigned long long)(unsigned)__builtin_amdgcn_readlane(__float_as_int(bm), 63) << 32)
      | (unsigned)~(unsigned)__builtin_amdgcn_readlane(bp, 63);
    if ((TID & 63) == 63) red2[i&1][TID>>6] = key;
    __syncthreads();
    unsigned long long kk = red2[i&1][0];
#pragma unroll
    for (int t = 1; t < NT/64; t++){
      unsigned long long o = red2[i&1][t];
      kk = kk > o ? kk : o;
    }
    far = (int)~(unsigned)kk;
  }
  if (a.it1 < 512){
#pragma unroll
    for (int j = 0; j < LP; j++) dst[TID + NT*j] = dmin[j];
    if (TID == 0) a.far[ci] = far;
  }
}

// ---------------- small row-GEMM with optional BN(+relu) on input load -----
template<int C, int K, int FLP>
__global__ void __launch_bounds__(256) rowgemm_kernel(const float* __restrict__ in,
    const float* __restrict__ w, const float* __restrict__ bias, const float2* __restrict__ st2,
    float* __restrict__ out, int rows_per_g, FpsArgs fa)
{
  int bid = blockIdx.x;
  if constexpr (FLP > 0){
    if (bid < fa.nc){ fps_body<FLP,256>(fa, bid); return; }
    bid -= fa.nc;
  }
  constexpr int RPB = 256 / C;
  __shared__ float lin[RPB * K];
  size_t row0 = (size_t)bid * RPB;
  int g = (int)(row0 / rows_per_g);
  for (int i = TID; i < RPB*K; i += 256){
    float v = in[row0*(size_t)K + i];
    if (st2){ float2 s = st2[(size_t)g*K + (i % K)]; v = fmaxf((v - s.x)*s.y, 0.f); }
    lin[i] = v;
  }
  __syncthreads();
  int r = TID / C, c = TID % C;
  float acc = bias[(size_t)g*C + c];
  const float* wg = w + (size_t)g*K*C + c;
#pragma unroll
  for (int k = 0; k < K; k++) acc = fmaf(lin[r*K + k], wg[(size_t)k*C], acc);
  out[(row0 + r)*C + c] = acc;
}

// ---------------- c2 layer via MFMA: 128 rows x 128 cols, K=64 -------------
// A = relu(BN(c1o)) bf16 frags in regs; B = pre-transposed weights in LDS.
template<int FLP>
__global__ void __launch_bounds__(256, 4) c2m_kernel(const float* __restrict__ in,
    const float2* __restrict__ st1, const short* __restrict__ wt,
    const float* __restrict__ bias, float* __restrict__ out, int rows_per_g, FpsArgs fa)
{
  int bid = blockIdx.x;
  if constexpr (FLP > 0){
    if (bid < fa.nc){ fps_body<FLP,256>(fa, bid); return; }
    bid -= fa.nc;
  }
  size_t row0 = (size_t)bid * 128;
  int g = (int)(row0 / rows_per_g);
  __shared__ short Bls[8192];      // [128c][64k] bf16, chunk-XOR swizzled
  __shared__ float2 sb[64];
  if (TID < 64) sb[TID] = st1[(size_t)g*64 + TID];
  {
    const short* wg = wt + (size_t)g*8192;
    for (int i = TID; i < 1024; i += 256){
      int c = i >> 3, kc = i & 7;
      short8 v = *(const short8*)&wg[c*64 + kc*8];
      *(short8*)&Bls[c*64 + ((kc ^ (c & 7)) << 3)] = v;
    }
  }
  __syncthreads();
  int lane = TID & 63, wid = TID >> 6, lr = lane & 15, lkg = lane >> 4;

  short8 afr[2][2];
  const float* src = in + row0*64;
#pragma unroll
  for (int kt = 0; kt < 2; kt++){
    int kb = kt*32 + lkg*8;
    float2 ss[8];
#pragma unroll
    for (int j = 0; j < 8; j++) ss[j] = sb[kb + j];
#pragma unroll
    for (int nt = 0; nt < 2; nt++){
      int row = wid*32 + nt*16 + lr;
      float4 a0 = *(const float4*)(src + row*64 + kb);
      float4 a1 = *(const float4*)(src + row*64 + kb + 4);
      const float vals[8] = {a0.x,a0.y,a0.z,a0.w,a1.x,a1.y,a1.z,a1.w};
      short8 ob;
#pragma unroll
      for (int j = 0; j < 8; j++)
        ob[j] = bf16rne(fmaxf((vals[j] - ss[j].x)*ss[j].y, 0.f));
      afr[kt][nt] = ob;
    }
  }

  f32x4 acc[2][8];
#pragma unroll
  for (int nt = 0; nt < 2; nt++)
#pragma unroll
    for (int et = 0; et < 8; et++) acc[nt][et] = (f32x4){0.f,0.f,0.f,0.f};
#pragma unroll
  for (int kt = 0; kt < 2; kt++){
#pragma unroll
    for (int et = 0; et < 8; et++){
      int e = et*16 + lr;
      short8 bfr = *(const short8*)&Bls[e*64 + (((kt*4 + lkg) ^ (e & 7)) << 3)];
      acc[0][et] = __builtin_amdgcn_mfma_f32_16x16x32_bf16(afr[kt][0], bfr, acc[0][et], 0, 0, 0);
      acc[1][et] = __builtin_amdgcn_mfma_f32_16x16x32_bf16(afr[kt][1], bfr, acc[1][et], 0, 0, 0);
    }
  }

#pragma unroll
  for (int et = 0; et < 8; et++){
    float bv = bias[(size_t)g*128 + et*16 + lr];
#pragma unroll
    for (int nt = 0; nt < 2; nt++)
#pragma unroll
      for (int r = 0; r < 4; r++){
        int row = wid*32 + nt*16 + lkg*4 + r;
        out[(row0 + row)*128 + et*16 + lr] = acc[nt][et][r] + bv;
      }
  }
}

// ---------------- pointnet L3 via MFMA: 128 rows/block, 8 col-slabs --------
template<int FLP>
__global__ void __launch_bounds__(256, 4) big1024m_kernel(const float* __restrict__ in,
    const float2* __restrict__ st2, const short* __restrict__ wtp,
    float* __restrict__ ps, float* __restrict__ pq, unsigned* __restrict__ maxenc, FpsArgs fa)
{
  int bid = blockIdx.x;
  if constexpr (FLP > 0){
    if (bid < fa.nc){ fps_body<FLP,256>(fa, bid); return; }
    bid -= fa.nc;
  }
  size_t row0 = (size_t)bid * 128;
  int b = (int)(row0 >> 11);
  __shared__ float2 sb[128];
  __shared__ float mS[512], mQ[512], mM[512];
  if (TID < 128) sb[TID] = st2[TID];
  __syncthreads();
  int lane = TID & 63, wid = TID >> 6, lr = lane & 15, lkg = lane >> 4;

  short8 afr[4][2];
  const float* src = in + row0*128;
#pragma unroll
  for (int kt = 0; kt < 4; kt++){
    int kb = kt*32 + lkg*8;
    float2 ss[8];
#pragma unroll
    for (int j = 0; j < 8; j++) ss[j] = sb[kb + j];
#pragma unroll
    for (int nt = 0; nt < 2; nt++){
      int row = wid*32 + nt*16 + lr;
      float4 a0 = *(const float4*)(src + row*128 + kb);
      float4 a1 = *(const float4*)(src + row*128 + kb + 4);
      const float vals[8] = {a0.x,a0.y,a0.z,a0.w,a1.x,a1.y,a1.z,a1.w};
      short8 ob;
#pragma unroll
      for (int j = 0; j < 8; j++)
        ob[j] = bf16rne(fmaxf((vals[j] - ss[j].x)*ss[j].y, 0.f));
      afr[kt][nt] = ob;
    }
  }

  for (int cs = 0; cs < 8; cs++){
    f32x4 acc[2][8];
#pragma unroll
    for (int nt = 0; nt < 2; nt++)
#pragma unroll
      for (int et = 0; et < 8; et++) acc[nt][et] = (f32x4){0.f,0.f,0.f,0.f};
    const short* wp = wtp + (size_t)(cs*128)*128;
#pragma unroll
    for (int kt = 0; kt < 4; kt++){
      int kb = kt*32 + lkg*8;
#pragma unroll
      for (int et = 0; et < 8; et++){
        short8 bfr = *(const short8*)&wp[(et*16 + lr)*128 + kb];
        acc[0][et] = __builtin_amdgcn_mfma_f32_16x16x32_bf16(afr[kt][0], bfr, acc[0][et], 0, 0, 0);
        acc[1][et] = __builtin_amdgcn_mfma_f32_16x16x32_bf16(afr[kt][1], bfr, acc[1][et], 0, 0, 0);
      }
    }
#pragma unroll
    for (int et = 0; et < 8; et++){
      float s = 0.f, q = 0.f, m = -1e38f;
#pragma unroll
      for (int nt = 0; nt < 2; nt++)
#pragma unroll
        for (int r = 0; r < 4; r++){
          float v = acc[nt][et][r];
          s += v; q = fmaf(v, v, q); m = fmaxf(m, v);
        }
      s += __shfl_xor(s, 16); s += __shfl_xor(s, 32);
      q += __shfl_xor(q, 16); q += __shfl_xor(q, 32);
      m = fmaxf(m, __shfl_xor(m, 16)); m = fmaxf(m, __shfl_xor(m, 32));
      if (lkg == 0){
        mS[wid*128 + et*16 + lr] = s;
        mQ[wid*128 + et*16 + lr] = q;
        mM[wid*128 + et*16 + lr] = m;
      }
    }
    __syncthreads();
    if (wid == 0){
#pragma unroll
      for (int t = 0; t < 2; t++){
        int c = t*64 + lane;
        float s4 = mS[c] + mS[128 + c] + mS[256 + c] + mS[384 + c];
        float q4 = mQ[c] + mQ[128 + c] + mQ[256 + c] + mQ[384 + c];
        float m4 = fmaxf(fmaxf(mM[c], mM[128 + c]), fmaxf(mM[256 + c], mM[384 + c]));
        ps[(size_t)bid*1024 + cs*128 + c] = s4;
        pq[(size_t)bid*1024 + cs*128 + c] = q4;
        atomicMax(&maxenc[(size_t)b*1024 + cs*128 + c], fenc(m4));
      }
    }
    __syncthreads();
  }
}

// ---------------- mapping GEMM v2: 8b x 4j tile, broadcast LDS lin ---------
template<int FLP>
__global__ void __launch_bounds__(128) mapgemm2_kernel(const float* __restrict__ in, int in_gstride,
    const float* __restrict__ w, const float* __restrict__ bias, const float2* __restrict__ st2,
    float* __restrict__ out, int K, int J, int JB, int NS, FpsArgs fa)
{
  int bid = blockIdx.x;
  if constexpr (FLP > 0){
    if (bid < fa.nc){ fps_body<FLP,128>(fa, bid); return; }
    bid -= fa.nc;
  }
  int kc = bid / (JB*16);
  int g  = (bid / JB) % 16;
  int jb = bid % JB;
  int kchunk = K / NS, k0 = kc*kchunk;
  __shared__ float linT[128*16];
  const float* ing = in + (size_t)g * in_gstride;
  for (int i = TID; i < kchunk*16; i += 128){
    int b = i / kchunk, k = i - b*kchunk;
    float v = ing[(size_t)b*K + k0 + k];
    if (st2){ float2 s = st2[(size_t)g*K + k0 + k]; v = fmaxf((v - s.x)*s.y, 0.f); }
    linT[k*16 + b] = v;
  }
  __syncthreads();
  int bh = TID >> 6, jq = TID & 63;
  int j = jb*256 + jq*4;
  const float* wp = w + ((size_t)g*K + k0)*J + j;
  float4 a4[8];
#pragma unroll
  for (int bi = 0; bi < 8; bi++) a4[bi] = make_float4(0.f,0.f,0.f,0.f);
#pragma unroll 4
  for (int k = 0; k < kchunk; k++){
    float4 wv = *(const float4*)(wp + (size_t)k*J);
    float4 l0 = *(const float4*)&linT[k*16 + bh*8];
    float4 l1 = *(const float4*)&linT[k*16 + bh*8 + 4];
    const float lv[8] = {l0.x,l0.y,l0.z,l0.w,l1.x,l1.y,l1.z,l1.w};
#pragma unroll
    for (int bi = 0; bi < 8; bi++){
      a4[bi].x = fmaf(lv[bi], wv.x, a4[bi].x);
      a4[bi].y = fmaf(lv[bi], wv.y, a4[bi].y);
      a4[bi].z = fmaf(lv[bi], wv.z, a4[bi].z);
      a4[bi].w = fmaf(lv[bi], wv.w, a4[bi].w);
    }
  }
  if (NS == 1){
    float4 bv = *(const float4*)(bias + (size_t)g*J + j);
#pragma unroll
    for (int bi = 0; bi < 8; bi++){
      int b = bh*8 + bi;
      float4 o = make_float4(a4[bi].x+bv.x, a4[bi].y+bv.y, a4[bi].z+bv.z, a4[bi].w+bv.w);
      *(float4*)&out[((size_t)g*16 + b)*J + j] = o;
    }
  } else {
#pragma unroll
    for (int bi = 0; bi < 8; bi++)
      *(float4*)&out[(((size_t)kc*16 + g)*16 + bh*8 + bi)*J + j] = a4[bi];
  }
}

// ---------------- old skinny per-g GEMM (kept for mp_w4, J=128; NS chunk
// must be a multiple of 128 -- stage stride is hard-wired) ------------------
__global__ void __launch_bounds__(256) mapgemm_kernel(const float* __restrict__ in, int in_gstride,
    const float* __restrict__ w, const float* __restrict__ bias, const float2* __restrict__ st2,
    float* __restrict__ out, int K, int J, int JB, int NS)
{
  int bid = blockIdx.x;
  int kc = bid / (JB*16);
  int g  = (bid / JB) % 16;
  int jb = bid % JB;
  int j  = jb*256 + TID;
  bool jv = j < J;
  int jc = jv ? j : 0;
  int kchunk = K / NS;
  int k0 = kc * kchunk;
  __shared__ float lin[16 * 128];
  const float* ing = in + (size_t)g * in_gstride;
  float acc[16];
  float bv = (NS == 1 && jv) ? bias[(size_t)g*J + jc] : 0.f;
#pragma unroll
  for (int b = 0; b < 16; b++) acc[b] = bv;
  for (int kt = k0; kt < k0 + kchunk; kt += 128){
    __syncthreads();
    for (int i = TID; i < 2048; i += 256){
      int b = i >> 7, k = i & 127;
      float v = ing[(size_t)b*K + kt + k];
      if (st2){ float2 s = st2[(size_t)g*K + kt + k]; v = fmaxf((v - s.x)*s.y, 0.f); }
      lin[i] = v;
    }
    __syncthreads();
    const float* wg = w + ((size_t)g*K + kt)*J + jc;
    for (int k = 0; k < 128; k++){
      float wv = wg[(size_t)k*J];
#pragma unroll
      for (int b = 0; b < 16; b++) acc[b] = fmaf(lin[b*128 + k], wv, acc[b]);
    }
  }
  if (jv){
    if (NS == 1){
      for (int b = 0; b < 16; b++) out[((size_t)g*16 + b)*J + j] = acc[b];
    } else {
      for (int b = 0; b < 16; b++) out[(((size_t)kc*16 + g)*16 + b)*J + j] = acc[b];
    }
  }
}

__global__ void __launch_bounds__(256) redstats_kernel(const float* __restrict__ part,
    const float* __restrict__ bias, float* __restrict__ out, float2* __restrict__ st2,
    int J, int NS)
{
  int t = blockIdx.x*256 + TID;
  int g = t / J, j = t % J;
  float bv = bias[t];
  float s = 0.f, q = 0.f;
  for (int b = 0; b < 16; b++){
    float v = bv;
    for (int c = 0; c < NS; c++) v += part[(((size_t)c*16 + g)*16 + b)*J + j];
    out[((size_t)g*16 + b)*J + j] = v;
    s += v; q = fmaf(v, v, q);
  }
  float mean = s * (1.f/16.f);
  float var  = q * (1.f/16.f) - mean*mean;
  st2[t] = make_float2(mean, rsqrtf(fmaxf(var, 0.f) + EPSf));
}

// chunked coalesced BN partial sums (optionally hosts fps sidecar) ----------
template<int FLP>
__global__ void __launch_bounds__(256) statsacc_kernel(const float* __restrict__ in,
    float* __restrict__ part, int C, size_t chunk, FpsArgs fa)
{
  int bid = blockIdx.x;
  if constexpr (FLP > 0){
    if (bid < fa.nc){ fps_body<FLP,256>(fa, bid); return; }
    bid -= fa.nc;
  }
  size_t base = (size_t)bid * chunk;
  int c = TID % C;
  float s = 0.f, q = 0.f;
  for (size_t idx = base + TID; idx < base + chunk; idx += 256){
    float v = in[idx]; s += v; q = fmaf(v, v, q);
  }
  __shared__ float ls[256], lq[256];
  ls[TID] = s; lq[TID] = q; __syncthreads();
  if (TID < C){
    for (int t = TID + C; t < 256; t += C){ s += ls[t]; q += lq[t]; }
    part[((size_t)bid*C + c)*2]   = s;
    part[((size_t)bid*C + c)*2+1] = q;
  }
}

__global__ void statsfin_kernel(const float* __restrict__ part, float2* __restrict__ st2,
    int C, int G, float invR)
{
  int slot = blockIdx.x*256 + TID;
  if (slot >= G*C) return;
  int g = slot / C, c = slot % C;
  int bpg = 256 / G;
  float s = 0.f, q = 0.f;
  for (int b = 0; b < bpg; b++){
    size_t p = ((size_t)(g*bpg + b)*C + c)*2;
    s += part[p]; q += part[p+1];
  }
  float mean = s*invR;
  float var  = q*invR - mean*mean;
  st2[slot] = make_float2(mean, rsqrtf(fmaxf(var, 0.f) + EPSf));
}

// PointNet L3: reduce 256 per-block partials -> per-channel (mean,rstd) -----
__global__ void pnfin_kernel(const float* __restrict__ ps, const float* __restrict__ pq,
                             float2* __restrict__ st)
{
  int c = blockIdx.x*256 + TID;
  float s = 0.f, q = 0.f;
  for (int rb = 0; rb < 256; rb++){ s += ps[rb*1024 + c]; q += pq[rb*1024 + c]; }
  float mean = s * (1.f/32768.f);
  float var  = q * (1.f/32768.f) - mean*mean;
  st[c] = make_float2(mean, rsqrtf(fmaxf(var, 0.f) + EPSf));
}

__global__ void feat_kernel(const unsigned* __restrict__ me, const float2* __restrict__ st,
                            float* __restrict__ feat)
{
  int t = blockIdx.x*256 + TID;
  int c = t & 1023;
  float2 s = st[c];
  feat[t] = (fdec(me[t]) - s.x) * s.y;
}

// ---------------- W transpose+cvt: Wt[g][e][k] bf16 (128k x 1024e per g) ---
__global__ void __launch_bounds__(256) wtr_kernel(const float* __restrict__ c3w,
                                                  short* __restrict__ wt)
{
  int g = blockIdx.x >> 4, kt = blockIdx.x & 15;
  __shared__ float lds[8*1024];
  const float* src = c3w + ((size_t)g*128 + kt*8)*1024;
  for (int i = TID; i < 8192; i += 256) lds[i] = src[i];
  __syncthreads();
  for (int e = TID; e < 1024; e += 256){
    short8 v;
#pragma unroll
    for (int j = 0; j < 8; j++) v[j] = bf16rne(lds[j*1024 + e]);
    *(short8*)&wt[((size_t)g*1024 + e)*128 + kt*8] = v;
  }
}

// ---------------- small W transpose+cvt: [G][64k][128c] -> [G][128c][64k] --
__global__ void __launch_bounds__(256) wtr2_kernel(const float* __restrict__ w,
                                                   short* __restrict__ wt)
{
  int g = blockIdx.x;
  __shared__ float lds[8192];
  const float* src = w + (size_t)g*8192;
  for (int i = TID; i < 8192; i += 256) lds[i] = src[i];
  __syncthreads();
  for (int i = TID; i < 1024; i += 256){
    int c = i >> 3, kc = i & 7;
    short8 v;
#pragma unroll
    for (int j = 0; j < 8; j++) v[j] = bf16rne(lds[(kc*8 + j)*128 + c]);
    *(short8*)&wt[(size_t)g*8192 + c*64 + kc*8] = v;
  }
}

// ---------------- fused v4.3: B staging software-pipelined, 2 barriers/eb --
template<int FLP>
__global__ void __launch_bounds__(256, 2) fused_kernel(const float* __restrict__ c2o,
    const float2* __restrict__ st2, const short* __restrict__ wt,
    const float* __restrict__ xb, const float* __restrict__ c4w, const float* __restrict__ c4b,
    float* __restrict__ out_pts, float* __restrict__ out_x1, FpsArgs fa)
{
  int bid = blockIdx.x;
  if constexpr (FLP > 0){
    if (bid < fa.nc){ fps_body<FLP,256>(fa, bid); return; }
    bid -= fa.nc;
  }
  int gb = bid >> 1, ebh = bid & 1;
  int g = gb >> 4, b = gb & 15;
  __shared__ short Pbf[16384];
  __shared__ short Bls[16384];
  __shared__ short xbT[4096];
  __shared__ float2 sb[128];
  __shared__ float mred[512];

  if (TID < 128) sb[TID] = st2[(size_t)g*128 + TID];
  {
    const float* xsrc = xb + (size_t)gb*4096;
    for (int idx = TID; idx < 1024; idx += 256){
      int n = idx >> 3, k4 = (idx & 7)*4;
      float4 v = *(const float4*)(xsrc + n*32 + k4);
      const float vv[4] = {v.x, v.y, v.z, v.w};
#pragma unroll
      for (int j = 0; j < 4; j++){
        int k = k4 + j;
        xbT[k*128 + (((n >> 3) ^ (k & 7)) << 3) + (n & 7)] = bf16rne(vv[j]);
      }
    }
  }
  const int eb0 = ebh*4;
  const short* wt_base = wt + (size_t)g*1024*128;
  {
    const short* wtg = wt_base + (size_t)(eb0*128)*128;
    for (int i = TID; i < 2048; i += 256){
      int e = i >> 4, kc = i & 15;
      short8 v = *(const short8*)&wtg[e*128 + kc*8];
      *(short8*)&Bls[e*128 + ((kc ^ (e & 7)) << 3)] = v;
    }
  }

  int lane = TID & 63, wid = TID >> 6;
  int lr = lane & 15, lkg = lane >> 4;

  __syncthreads();   // S0: sb + xbT + Bls(eb0) ready

  short8 afr[4][2];
  const float* src = c2o + (size_t)gb*16384;
#pragma unroll
  for (int kt = 0; kt < 4; kt++){
    int kb = kt*32 + lkg*8;
    float2 ss[8];
#pragma unroll
    for (int j = 0; j < 8; j++) ss[j] = sb[kb + j];
#pragma unroll
    for (int nt = 0; nt < 2; nt++){
      int row = wid*32 + nt*16 + lr;
      float4 a0 = *(const float4*)(src + row*128 + kb);
      float4 a1 = *(const float4*)(src + row*128 + kb + 4);
      const float vals[8] = {a0.x,a0.y,a0.z,a0.w,a1.x,a1.y,a1.z,a1.w};
      short8 ob;
#pragma unroll
      for (int j = 0; j < 8; j++)
        ob[j] = bf16rne(fmaxf((vals[j] - ss[j].x)*ss[j].y, 0.f));
      afr[kt][nt] = ob;
    }
  }

  float c4l[2][3];
  {
    const float* cw = c4w + g*96;
#pragma unroll
    for (int kt2 = 0; kt2 < 2; kt2++){
      int k = kt2*16 + lr;
      c4l[kt2][0] = cw[k*3+0]; c4l[kt2][1] = cw[k*3+1]; c4l[kt2][2] = cw[k*3+2];
    }
  }
  float cb0 = c4b[g*3+0], cb1 = c4b[g*3+1], cb2 = c4b[g*3+2];
  unsigned* Pu = (unsigned*)Pbf;

  for (int eb = eb0; eb < eb0 + 4; eb++){
    f32x4 acc[2][8];
#pragma unroll
    for (int nt = 0; nt < 2; nt++)
#pragma unroll
      for (int et = 0; et < 8; et++) acc[nt][et] = (f32x4){0.f,0.f,0.f,0.f};
#pragma unroll
    for (int kt = 0; kt < 4; kt++){
      int kcf = kt*4 + lkg;
#pragma unroll
      for (int et = 0; et < 8; et++){
        int e = et*16 + lr;
        short8 bfr = *(const short8*)&Bls[e*128 + ((kcf ^ (e & 7)) << 3)];
        acc[0][et] = __builtin_amdgcn_mfma_f32_16x16x32_bf16(afr[kt][0], bfr, acc[0][et], 0, 0, 0);
        acc[1][et] = __builtin_amdgcn_mfma_f32_16x16x32_bf16(afr[kt][1], bfr, acc[1][et], 0, 0, 0);
      }
    }

    short8 bpre[8];
    bool havepre = (eb + 1 < eb0 + 4);
    if (havepre){
      const short* wtg = wt_base + (size_t)((eb+1)*128)*128;
#pragma unroll
      for (int ii = 0; ii < 8; ii++){
        int i = TID + 256*ii;
        int e = i >> 4, kc = i & 15;
        bpre[ii] = *(const short8*)&wtg[e*128 + kc*8];
      }
    }

#pragma unroll
    for (int et = 0; et < 8; et++){
      float ss = 0.f;
#pragma unroll
      for (int nt = 0; nt < 2; nt++)
#pragma unroll
        for (int r = 0; r < 4; r++){
          float p = __expf(acc[nt][et][r]);
          acc[nt][et][r] = p;
          ss += p;
        }
      ss += __shfl_xor(ss, 16);
      ss += __shfl_xor(ss, 32);
      if (lkg == 0) mred[wid*128 + et*16 + lr] = ss;
      int e = et*16 + lr;
#pragma unroll
      for (int nt = 0; nt < 2; nt++){
        int nb = wid*32 + nt*16 + lkg*4;
        int base = e*128 + ((((nb >> 3)) ^ (e & 7)) << 3) + (nb & 7);
        unsigned lo = (unsigned)(unsigned short)bf16rne(acc[nt][et][0])
                    | ((unsigned)(unsigned short)bf16rne(acc[nt][et][1]) << 16);
        unsigned hi = (unsigned)(unsigned short)bf16rne(acc[nt][et][2])
                    | ((unsigned)(unsigned short)bf16rne(acc[nt][et][3]) << 16);
        Pu[base >> 1]       = lo;
        Pu[(base >> 1) + 1] = hi;
      }
    }
    __syncthreads();   // S3

    if (havepre){
#pragma unroll
      for (int ii = 0; ii < 8; ii++){
        int i = TID + 256*ii;
        int e = i >> 4, kc = i & 15;
        *(short8*)&Bls[e*128 + ((kc ^ (e & 7)) << 3)] = bpre[ii];
      }
    }

    f32x4 yy[2][2];
#pragma unroll
    for (int t2 = 0; t2 < 2; t2++){ yy[t2][0] = (f32x4){0.f,0.f,0.f,0.f}; yy[t2][1] = (f32x4){0.f,0.f,0.f,0.f}; }
#pragma unroll
    for (int nc = 0; nc < 4; nc++){
      short8 bfrs[2];
#pragma unroll
      for (int kt2 = 0; kt2 < 2; kt2++){
        int k = kt2*16 + lr;
        bfrs[kt2] = *(const short8*)&xbT[k*128 + (((nc*4 + lkg) ^ (k & 7)) << 3)];
      }
#pragma unroll
      for (int t2 = 0; t2 < 2; t2++){
        int e = (wid*2 + t2)*16 + lr;
        short8 afrp = *(const short8*)&Pbf[e*128 + (((nc*4 + lkg) ^ (e & 7)) << 3)];
        yy[t2][0] = __builtin_amdgcn_mfma_f32_16x16x32_bf16(afrp, bfrs[0], yy[t2][0], 0, 0, 0);
        yy[t2][1] = __builtin_amdgcn_mfma_f32_16x16x32_bf16(afrp, bfrs[1], yy[t2][1], 0, 0, 0);
      }
    }

#pragma unroll
    for (int t2 = 0; t2 < 2; t2++){
#pragma unroll
      for (int r = 0; r < 4; r++){
        float o0 = yy[t2][0][r]*c4l[0][0] + yy[t2][1][r]*c4l[1][0];
        float o1 = yy[t2][0][r]*c4l[0][1] + yy[t2][1][r]*c4l[1][1];
        float o2 = yy[t2][0][r]*c4l[0][2] + yy[t2][1][r]*c4l[1][2];
#pragma unroll
        for (int d = 1; d < 16; d <<= 1){
          o0 += __shfl_xor(o0, d);
          o1 += __shfl_xor(o1, d);
          o2 += __shfl_xor(o2, d);
        }
        if (lr == 0){
          int e = (wid*2 + t2)*16 + lkg*4 + r;
          float s = mred[e] + mred[128 + e] + mred[256 + e] + mred[384 + e];
          float rs = 1.f / s;
          o0 = fmaf(o0, rs, cb0);
          o1 = fmaf(o1, rs, cb1);
          o2 = fmaf(o2, rs, cb2);
          int eg = eb*128 + e;
          size_t po = ((size_t)gb*1024 + eg)*3;
          out_pts[po+0] = o0; out_pts[po+1] = o1; out_pts[po+2] = o2;
          if (out_x1){
            size_t xo = (((size_t)b*16 + g)*1024 + eg)*3;
            out_x1[xo+0] = o0; out_x1[xo+1] = o1; out_x1[xo+2] = o2;
          }
        }
      }
    }
    __syncthreads();   // S5
  }
}

// ---------------- x_2 = concat(fps1, x_partial) + d2 -----------------------
__global__ void combine_kernel(const float* __restrict__ fps1, const float* __restrict__ xpart,
                               const float* __restrict__ d2, float* __restrict__ x2)
{
  size_t i = (size_t)blockIdx.x*256 + TID;
  if (i >= (size_t)16*16*1024*3) return;
  int c = (int)(i % 3);
  size_t t = i / 3;
  int e = (int)(t % 1024);
  size_t gb = t / 1024;
  int g = (int)(gb >> 4), b = (int)(gb & 15);
  float base;
  if (e < 512) base = fps1[(gb*512 + e)*3 + c];
  else         base = xpart[((size_t)b*512 + (e - 512))*3 + c];
  x2[(((size_t)b*16384) + (size_t)g*1024 + e)*3 + c] = base + d2[i];
}

} // anon namespace

extern "C" void kernel_launch(void* const* d_in, const int* in_sizes, int n_in,
                              void* d_out, int out_size, void* d_ws, size_t ws_size,
                              hipStream_t stream)
{
  (void)in_sizes; (void)n_in; (void)out_size; (void)ws_size;
  const float* x    = (const float*)d_in[0];
  const float* pnw1 = (const float*)d_in[1];
  const float* pnb1 = (const float*)d_in[2];
  const float* pnb2 = (const float*)d_in[4];
  const float* pnw3 = (const float*)d_in[5];
  const float* mpw[4] = {(const float*)d_in[7],(const float*)d_in[9],(const float*)d_in[11],(const float*)d_in[13]};
  const float* mpb[4] = {(const float*)d_in[8],(const float*)d_in[10],(const float*)d_in[12],(const float*)d_in[14]};

  float* ws = (float*)d_ws;
  size_t o = 0;
  auto alloc = [&](size_t n){ float* p = ws + o; o += n; return p; };
  float* x_partial = alloc(24576);
  float* feat      = alloc(16384);
  float* mfeat     = alloc(32768);
  float2* st_pn1   = (float2*)alloc(128);
  float2* st_pn2   = (float2*)alloc(256);
  float2* st_pn3   = (float2*)alloc(2048);
  float2* st_c1    = (float2*)alloc(2048);
  float2* st_c2    = (float2*)alloc(4096);
  float2* st_map0  = (float2*)alloc(32768);
  float2* st_map1  = (float2*)alloc(32768);
  float2* st_map2  = (float2*)alloc(32768);
  float2* st_map3  = (float2*)alloc(4096);
  float* sa_part   = alloc(65536);
  float* pn_ps     = alloc(262144);
  float* pn_pq     = alloc(262144);
  unsigned* maxenc = (unsigned*)alloc(16384);
  float* mapA      = alloc(262144);
  float* mapB      = alloc(262144);
  float* mpart     = alloc(4194304);
  float* xb        = alloc(1048576);
  float* c1o       = alloc(2097152);
  float* c2o       = alloc(4194304);
  float* x1g       = alloc(786432);
  float* d2buf     = alloc(786432);
  float* fps1b     = alloc(393216);
  float* fpsA_dmin = alloc(32768);
  int*   fpsA_far  = (int*)alloc(16);
  float* fpsB_dmin = alloc(262144);
  int*   fpsB_far  = (int*)alloc(256);
  short* wt_g      = (short*)alloc(1048576);
  short* wt_r      = (short*)alloc(1048576);
  short* wt_pn     = (short*)alloc(65536);     // 128x1024 bf16
  short* wt_pn2    = (short*)alloc(4096);      // 1x128x64 bf16
  short* wt_c2g    = (short*)alloc(65536);     // 16x128x64 bf16
  short* wt_c2r    = (short*)alloc(65536);     // 16x128x64 bf16

  float* xout1 = (float*)d_out;
  float* xout2 = xout1 + 786432;

  hipMemsetAsync(maxenc, 0, 16384*sizeof(unsigned), stream);

  wtr_kernel<<<256, 256, 0, stream>>>((const float*)d_in[21], wt_g);
  wtr_kernel<<<256, 256, 0, stream>>>((const float*)d_in[31], wt_r);
  wtr_kernel<<<16, 256, 0, stream>>>(pnw3, wt_pn);
  wtr2_kernel<<<1, 256, 0, stream>>>((const float*)d_in[3],  wt_pn2);
  wtr2_kernel<<<16, 256, 0, stream>>>((const float*)d_in[19], wt_c2g);
  wtr2_kernel<<<16, 256, 0, stream>>>((const float*)d_in[29], wt_c2r);

  FpsArgs f0{};
  FpsArgs fa{x, x_partial, fpsA_dmin, fpsA_far, 0, 0, 16};

  // ---- PointNet (fps-A rides as sidecar) ----
  fa.it0 = 0; fa.it1 = 64;
  rowgemm_kernel<64,3,8><<<8192+16, 256, 0, stream>>>(x, pnw1, pnb1, nullptr, c1o, 32768, fa);
  statsacc_kernel<0><<<256, 256, 0, stream>>>(c1o, sa_part, 64, 8192, f0);
  statsfin_kernel<<<1, 256, 0, stream>>>(sa_part, st_pn1, 64, 1, 1.f/32768.f);
  fa.it0 = 64; fa.it1 = 128;
  c2m_kernel<8><<<256+16, 256, 0, stream>>>(c1o, st_pn1, wt_pn2, pnb2, c2o, 32768, fa);
  statsacc_kernel<0><<<256, 256, 0, stream>>>(c2o, sa_part, 128, 16384, f0);
  statsfin_kernel<<<1, 256, 0, stream>>>(sa_part, st_pn2, 128, 1, 1.f/32768.f);
  fa.it0 = 128; fa.it1 = 224;
  big1024m_kernel<8><<<256+16, 256, 0, stream>>>(c2o, st_pn2, wt_pn, pn_ps, pn_pq, maxenc, fa);
  pnfin_kernel<<<4, 256, 0, stream>>>(pn_ps, pn_pq, st_pn3);
  feat_kernel<<<64, 256, 0, stream>>>(maxenc, st_pn3, feat);

  // ---- Mapping MLP ----
  fa.it0 = 224; fa.it1 = 288;
  mapgemm2_kernel<16><<<1024+16, 128, 0, stream>>>(feat, 0,     mpw[0], nullptr, nullptr, mpart, 1024, 1024, 4, 16, fa);
  redstats_kernel<<<64, 256, 0, stream>>>(mpart, mpb[0], mapA, st_map0, 1024, 16);
  fa.it0 = 288; fa.it1 = 352;
  mapgemm2_kernel<16><<<1024+16, 128, 0, stream>>>(mapA, 16384, mpw[1], nullptr, st_map0, mpart, 1024, 1024, 4, 16, fa);
  redstats_kernel<<<64, 256, 0, stream>>>(mpart, mpb[1], mapB, st_map1, 1024, 16);
  fa.it0 = 352; fa.it1 = 416;
  mapgemm2_kernel<16><<<1024+16, 128, 0, stream>>>(mapB, 16384, mpw[2], nullptr, st_map1, mpart, 1024, 1024, 4, 16, fa);
  redstats_kernel<<<64, 256, 0, stream>>>(mpart, mpb[2], mapA, st_map2, 1024, 16);
  // mp_w4: NS=4 (kchunk must stay a multiple of 128)
  mapgemm_kernel<<<64, 256, 0, stream>>>(mapA, 16384, mpw[3], nullptr, st_map2, mpart, 1024, 128, 1, 4);
  redstats_kernel<<<8, 256, 0, stream>>>(mpart, mpb[3], mfeat, st_map3, 128, 4);

  // ---- Two AXform heads; fps-A finishes on head-0, fps-B rides head-1 ----
  for (int p = 0; p < 2; p++){
    const float* fw  = (const float*)d_in[15 + p*10 + 0];
    const float* fb  = (const float*)d_in[15 + p*10 + 1];
    const float* c1w = (const float*)d_in[15 + p*10 + 2];
    const float* c1b = (const float*)d_in[15 + p*10 + 3];
    const float* c2b = (const float*)d_in[15 + p*10 + 5];
    const float* c4w = (const float*)d_in[15 + p*10 + 8];
    const float* c4b = (const float*)d_in[15 + p*10 + 9];
    const short* wtc2 = (p == 0) ? wt_c2g : wt_c2r;

    if (p == 0){
      fa.it0 = 416; fa.it1 = 480;
      mapgemm2_kernel<16><<<256+16, 128, 0, stream>>>(mfeat, 2048, fw, fb, st_map3, xb, 128, 4096, 16, 1, fa);
      fa.it0 = 480; fa.it1 = 512;
      rowgemm_kernel<64,32,8><<<8192+16, 256, 0, stream>>>(xb, c1w, c1b, nullptr, c1o, 2048, fa);
      statsacc_kernel<0><<<256, 256, 0, stream>>>(c1o, sa_part, 64, 8192, f0);
      statsfin_kernel<<<4, 256, 0, stream>>>(sa_part, st_c1, 64, 16, 1.f/2048.f);
      c2m_kernel<0><<<256, 256, 0, stream>>>(c1o, st_c1, wtc2, c2b, c2o, 2048, f0);
      statsacc_kernel<0><<<256, 256, 0, stream>>>(c2o, sa_part, 128, 16384, f0);
      statsfin_kernel<<<8, 256, 0, stream>>>(sa_part, st_c2, 128, 16, 1.f/2048.f);
      fused_kernel<0><<<512, 256, 0, stream>>>(c2o, st_c2, wt_g, xb, c4w, c4b, x1g, xout1, f0);
    } else {
      FpsArgs fb_{x1g, fps1b, fpsB_dmin, fpsB_far, 0, 0, 256};
      fb_.it0 = 0; fb_.it1 = 48;
      mapgemm2_kernel<8><<<256+256, 128, 0, stream>>>(mfeat, 2048, fw, fb, st_map3, xb, 128, 4096, 16, 1, fb_);
      fb_.it0 = 48; fb_.it1 = 144;
      rowgemm_kernel<64,32,4><<<8192+256, 256, 0, stream>>>(xb, c1w, c1b, nullptr, c1o, 2048, fb_);
      fb_.it0 = 144; fb_.it1 = 176;
      statsacc_kernel<4><<<256+256, 256, 0, stream>>>(c1o, sa_part, 64, 8192, fb_);
      statsfin_kernel<<<4, 256, 0, stream>>>(sa_part, st_c1, 64, 16, 1.f/2048.f);
      fb_.it0 = 176; fb_.it1 = 240;
      c2m_kernel<4><<<256+256, 256, 0, stream>>>(c1o, st_c1, wtc2, c2b, c2o, 2048, fb_);
      fb_.it0 = 240; fb_.it1 = 272;
      statsacc_kernel<4><<<256+256, 256, 0, stream>>>(c2o, sa_part, 128, 16384, fb_);
      statsfin_kernel<<<8, 256, 0, stream>>>(sa_part, st_c2, 128, 16, 1.f/2048.f);
      fb_.it0 = 272; fb_.it1 = 512;
      fused_kernel<4><<<512+256, 256, 0, stream>>>(c2o, st_c2, wt_r, xb, c4w, c4b, d2buf, nullptr, fb_);
    }
  }

  combine_kernel<<<3072, 256, 0, stream>>>(fps1b, x_partial, d2buf, xout2);
}